// Round 1
// baseline (788.112 us; speedup 1.0000x reference)
//
#include <hip/hip_runtime.h>
#include <math.h>

#define NENT 50000
#define NREL 500
#define DIM 256
#define BATCH 512
#define EPSV 1e-5f

// ws layout: floats [0,10240) = acc(4096) stats(4096) Kc(2048); then f16 tables
#define WS_ACC    0
#define WS_STATS  4096
#define WS_KC     8192
#define WS_F16    10240   // th: 4*512*256 halves, then Eh: 4*50000*256 halves

typedef _Float16 f16x8 __attribute__((ext_vector_type(8)));
typedef _Float16 f16x4 __attribute__((ext_vector_type(4)));
typedef float f32x4 __attribute__((ext_vector_type(4)));
typedef float f32x16 __attribute__((ext_vector_type(16)));

__device__ inline f32x16 zero16() {
    f32x16 v;
#pragma unroll
    for (int i = 0; i < 16; ++i) v[i] = 0.f;
    return v;
}

// ---------------- Phase 1: qnorm + f16 convert + BN stats over ALL entities ----------------
// Vectorized: 64 d-quads x 4 n-phases. float4 loads (16B/lane), f16x4 stores (8B/lane).
__global__ void convert_stats_kernel(const float* __restrict__ E, _Float16* __restrict__ Eh,
                                     float* __restrict__ acc) {
    __shared__ float red[3][64][33];   // j=1..3 partials (pad 33 vs 32: avoid bank conflict)
    int tid = threadIdx.x;
    int dq = tid & 63, j = tid >> 6;
    int d0 = dq * 4;
    int per = (NENT + gridDim.x - 1) / gridDim.x;
    int n0 = blockIdx.x * per;
    int n1 = n0 + per; if (n1 > NENT) n1 = NENT;

    float sm[4][4]; float sq[4][4];
#pragma unroll
    for (int c = 0; c < 4; ++c)
#pragma unroll
        for (int dd = 0; dd < 4; ++dd) { sm[c][dd] = 0.f; sq[c][dd] = 0.f; }

    for (int n = n0 + j; n < n1; n += 4) {
        size_t ga = (size_t)n * DIM + d0;
        f32x4 e[4];
        e[0] = *(const f32x4*)(E + ga);
        e[1] = *(const f32x4*)(E + (size_t)NENT * DIM + ga);
        e[2] = *(const f32x4*)(E + (size_t)2 * NENT * DIM + ga);
        e[3] = *(const f32x4*)(E + (size_t)3 * NENT * DIM + ga);
        float inv[4];
#pragma unroll
        for (int dd = 0; dd < 4; ++dd)
            inv[dd] = rsqrtf(e[0][dd]*e[0][dd] + e[1][dd]*e[1][dd] +
                             e[2][dd]*e[2][dd] + e[3][dd]*e[3][dd]);
#pragma unroll
        for (int c = 0; c < 4; ++c) {
            f16x4 hv;
#pragma unroll
            for (int dd = 0; dd < 4; ++dd) {
                float v = e[c][dd] * inv[dd];
                hv[dd] = (_Float16)v;
                sm[c][dd] += v; sq[c][dd] += v * v;
            }
            *(f16x4*)(Eh + (size_t)c * NENT * DIM + ga) = hv;
        }
    }

    if (j > 0) {
        float* p = &red[j-1][dq][0];
#pragma unroll
        for (int c = 0; c < 4; ++c)
#pragma unroll
            for (int dd = 0; dd < 4; ++dd) {
                p[c*4 + dd]      = sm[c][dd];
                p[16 + c*4 + dd] = sq[c][dd];
            }
    }
    __syncthreads();
    if (j == 0) {
#pragma unroll
        for (int c = 0; c < 4; ++c)
#pragma unroll
            for (int dd = 0; dd < 4; ++dd) {
                float s = sm[c][dd] + red[0][dq][c*4+dd] + red[1][dq][c*4+dd] + red[2][dq][c*4+dd];
                float q = sq[c][dd] + red[0][dq][16+c*4+dd] + red[1][dq][16+c*4+dd] + red[2][dq][16+c*4+dd];
                atomicAdd(&acc[c*DIM + d0 + dd], s);
                atomicAdd(&acc[1024 + c*DIM + d0 + dd], q);
            }
    }
}

// ---------------- Phase 2: BN stats over gathered batch h ----------------
__global__ void stats_batch_kernel(const float* __restrict__ E, const int* __restrict__ h_idx,
                                   float* __restrict__ accH) {
    int d = threadIdx.x;
    int b0 = blockIdx.x * 32;
    float sm0=0,sm1=0,sm2=0,sm3=0, sq0=0,sq1=0,sq2=0,sq3=0;
    for (int j = 0; j < 32; ++j) {
        int n = h_idx[b0 + j];
        int ga = n*DIM + d;
        float e0 = E[ga];
        float e1 = E[1*NENT*DIM + ga];
        float e2 = E[2*NENT*DIM + ga];
        float e3 = E[3*NENT*DIM + ga];
        float inv = rsqrtf(e0*e0+e1*e1+e2*e2+e3*e3);
        e0*=inv; e1*=inv; e2*=inv; e3*=inv;
        sm0+=e0; sq0+=e0*e0;
        sm1+=e1; sq1+=e1*e1;
        sm2+=e2; sq2+=e2*e2;
        sm3+=e3; sq3+=e3*e3;
    }
    atomicAdd(&accH[0*DIM+d], sm0); atomicAdd(&accH[1024 + 0*DIM+d], sq0);
    atomicAdd(&accH[1*DIM+d], sm1); atomicAdd(&accH[1024 + 1*DIM+d], sq1);
    atomicAdd(&accH[2*DIM+d], sm2); atomicAdd(&accH[1024 + 2*DIM+d], sq2);
    atomicAdd(&accH[3*DIM+d], sm3); atomicAdd(&accH[1024 + 3*DIM+d], sq3);
}

// ---------------- Phase 3: finalize stats ----------------
__global__ void finalize_stats_kernel(const float* __restrict__ acc, float* __restrict__ stats) {
    int i = blockIdx.x * blockDim.x + threadIdx.x;  // 0..1023 -> (c,d)
    float mE = acc[i] * (1.0f / NENT);
    float vE = acc[1024 + i] * (1.0f / NENT) - mE * mE;
    float mH = acc[2048 + i] * (1.0f / BATCH);
    float vH = acc[3072 + i] * (1.0f / BATCH) - mH * mH;
    stats[i]        = mE;
    stats[1024 + i] = rsqrtf(vE + EPSV);
    stats[2048 + i] = mH;
    stats[3072 + i] = rsqrtf(vH + EPSV);
}

// ---------------- Phase 4: build t' (BN-folded, f16) and K[c][b] ----------------
__global__ void build_t_kernel(const float* __restrict__ E, const float* __restrict__ R,
                               const float* __restrict__ psi_emb,
                               const float* __restrict__ gamma, const float* __restrict__ beta,
                               const int* __restrict__ h_idx, const int* __restrict__ r_idx,
                               const float* __restrict__ stats,
                               _Float16* __restrict__ th, float* __restrict__ Kc) {
    __shared__ float red[4];
    int b = blockIdx.x, d = threadIdx.x;
    int wave = d >> 6, lane = d & 63;
    int hn = h_idx[b], rn = r_idx[b];

    float hv[4];
    hv[0] = E[hn*DIM + d];
    hv[1] = E[1*NENT*DIM + hn*DIM + d];
    hv[2] = E[2*NENT*DIM + hn*DIM + d];
    hv[3] = E[3*NENT*DIM + hn*DIM + d];
    float invh = rsqrtf(hv[0]*hv[0]+hv[1]*hv[1]+hv[2]*hv[2]+hv[3]*hv[3]);
    float hq[4];
#pragma unroll
    for (int c = 0; c < 4; ++c) {
        float v = hv[c] * invh;
        float mH = stats[2048 + c*DIM + d], isH = stats[3072 + c*DIM + d];
        hq[c] = (v - mH) * isH * gamma[c*DIM + d] + beta[c*DIM + d];
    }

    float r0 = R[rn*DIM + d];
    float r1 = R[1*NREL*DIM + rn*DIM + d];
    float r2 = R[2*NREL*DIM + rn*DIM + d];
    float r3 = R[3*NREL*DIM + rn*DIM + d];
    float invr = rsqrtf(r0*r0+r1*r1+r2*r2+r3*r3);
    r0*=invr; r1*=invr; r2*=invr; r3*=invr;

    float p = psi_emb[rn*DIM + d];
    float cz = cosf(p), sz = sinf(p);

    float m1r = hq[0]*r0 - hq[1]*r1;
    float m1i = hq[0]*r1 + hq[1]*r0;
    float X   = hq[2]*r2 + hq[3]*r3;
    float Y   = hq[3]*r2 - hq[2]*r3;
    float m2r = cz*X - sz*Y;
    float m2i = cz*Y + sz*X;
    float m3r = hq[0]*r2 - hq[1]*r3;
    float m3i = hq[0]*r3 + hq[1]*r2;
    float U   = hq[2]*r0 + hq[3]*r1;
    float V   = hq[3]*r0 - hq[2]*r1;
    float m4r = cz*U - sz*V;
    float m4i = cz*V + sz*U;

    float t[4] = { m1r - m2r, m1i - m2i, m3r + m4r, m3i + m4i };

#pragma unroll
    for (int c = 0; c < 4; ++c) {
        float g   = gamma[c*DIM + d];
        float mE  = stats[c*DIM + d];
        float isE = stats[1024 + c*DIM + d];
        th[((size_t)c*BATCH + b)*DIM + d] = (_Float16)(t[c] * g * isE);
        float kp = t[c] * (beta[c*DIM + d] - g * mE * isE);
#pragma unroll
        for (int off = 32; off > 0; off >>= 1) kp += __shfl_down(kp, off, 64);
        if (lane == 0) red[wave] = kp;
        __syncthreads();
        if (d == 0) Kc[c*BATCH + b] = red[0] + red[1] + red[2] + red[3];
        __syncthreads();
    }
}

// ---------------- Phase 5: f16 MFMA GEMM + bias + sigmoid ----------------
// Block 128b x 128n, 4 waves (wave tile 64x64), K-chunk 32 (2 MFMA K-steps).
// DOUBLE-BUFFERED: stage chunk t+1 while computing chunk t; counted vmcnt(4)
// + raw s_barrier (no __syncthreads -> no forced vmcnt(0) drain at the barrier).
// XCD-chunked block swizzle with b-tile-fastest ordering so the 4 b-tiles of an
// n-tile run adjacent on one XCD -> Eh panel L2 reuse.
__launch_bounds__(256)
__global__ void score_gemm_kernel(const _Float16* __restrict__ th,  // [4][512][256]
                                  const _Float16* __restrict__ Eh,  // [4][50000][256]
                                  const float* __restrict__ Kc,     // [4][512]
                                  const float* __restrict__ biases, // [4][50000]
                                  float* __restrict__ out) {        // [4][512][50000]
    __shared__ __align__(1024) char smem[32768];   // 2 buffers x 16 frags x 1024B
    int tid = threadIdx.x;
    int w = tid >> 6, l = tid & 63;
    int lr = l & 31, lh = l >> 5;
    int wm = w & 1, wn = w >> 1;            // wave m-half / n-half

    // bijective chunked XCD swizzle: nwg = 391*4*4 = 6256 = 8 * 782
    int lin = blockIdx.x + (int)gridDim.x * (blockIdx.y + (int)gridDim.y * blockIdx.z);
    int wg  = (lin & 7) * 782 + (lin >> 3);
    int bt  = wg & 3;                       // b-tile fastest within a chunk
    int nt  = (wg >> 2) % 391;
    int c   = wg / 1564;                    // 391*4
    int b0  = bt * 128;
    int n0  = nt * 128;

    const _Float16* Ah = th + (size_t)c * BATCH * DIM;
    const _Float16* Bh = Eh + (size_t)c * NENT * DIM;

    f32x16 acc00 = zero16(), acc01 = zero16(), acc10 = zero16(), acc11 = zero16();

    // stage one 32-wide K-chunk (16 frags of 1024B) into buffer slot
    auto stage = [&](int kc, int slot) {
        int kbase = kc * 32;
#pragma unroll
        for (int i = 0; i < 4; ++i) {
            int f = w * 4 + i;
            const _Float16* gp;
            if (f < 8) {                          // A frag: mf=f>>1, ks=f&1
                int mf = f >> 1, ks = f & 1;
                gp = Ah + (size_t)(b0 + mf*32 + lr) * DIM + kbase + ks*16 + lh*8;
            } else {                              // B frag
                int g = f - 8, nf = g >> 1, ks = g & 1;
                int n = n0 + nf*32 + lr; if (n > NENT-1) n = NENT-1;
                gp = Bh + (size_t)n * DIM + kbase + ks*16 + lh*8;
            }
            __builtin_amdgcn_global_load_lds(
                (const __attribute__((address_space(1))) void*)gp,
                (__attribute__((address_space(3))) void*)(smem + slot * 16384 + f * 1024),
                16, 0, 0);
        }
    };

    auto compute = [&](int slot) {
        const char* s = smem + slot * 16384;
#pragma unroll
        for (int ks = 0; ks < 2; ++ks) {
            f16x8 a0  = *(const f16x8*)(s + ((wm*2+0)*2 + ks)*1024 + l*16);
            f16x8 a1  = *(const f16x8*)(s + ((wm*2+1)*2 + ks)*1024 + l*16);
            f16x8 bb0 = *(const f16x8*)(s + 8192 + ((wn*2+0)*2 + ks)*1024 + l*16);
            f16x8 bb1 = *(const f16x8*)(s + 8192 + ((wn*2+1)*2 + ks)*1024 + l*16);
            acc00 = __builtin_amdgcn_mfma_f32_32x32x16_f16(a0, bb0, acc00, 0, 0, 0);
            acc01 = __builtin_amdgcn_mfma_f32_32x32x16_f16(a0, bb1, acc01, 0, 0, 0);
            acc10 = __builtin_amdgcn_mfma_f32_32x32x16_f16(a1, bb0, acc10, 0, 0, 0);
            acc11 = __builtin_amdgcn_mfma_f32_32x32x16_f16(a1, bb1, acc11, 0, 0, 0);
        }
    };

    stage(0, 0);                                  // prologue: chunk 0 -> buf 0
    for (int t = 0; t < 7; ++t) {
        stage(t + 1, (t + 1) & 1);                // prefetch next chunk (4 loads/wave)
        asm volatile("s_waitcnt vmcnt(4)" ::: "memory");   // chunk t's loads done; t+1 in flight
        __builtin_amdgcn_s_barrier();
        compute(t & 1);
        __builtin_amdgcn_s_barrier();             // reads done before buf gets overwritten
    }
    asm volatile("s_waitcnt vmcnt(0)" ::: "memory");       // drain chunk 7
    __builtin_amdgcn_s_barrier();
    compute(1);                                   // chunk 7 -> buf 1

    // epilogue: D[m][n]: n = lane&31, m = (reg&3)+8*(reg>>2)+4*(lane>>5)
    const float* Kcc = Kc + c * BATCH;
    const float* bc  = biases + (size_t)c * NENT;
    float* oc = out + (size_t)c * BATCH * NENT;
#pragma unroll
    for (int mi = 0; mi < 2; ++mi) {
#pragma unroll
        for (int ni = 0; ni < 2; ++ni) {
            const f32x16& a = (mi==0) ? (ni==0 ? acc00 : acc01) : (ni==0 ? acc10 : acc11);
            int n = n0 + wn*64 + ni*32 + lr;
            bool ok = (n < NENT);
            float bv = ok ? bc[n] : 0.f;
#pragma unroll
            for (int reg = 0; reg < 16; ++reg) {
                int m = b0 + wm*64 + mi*32 + (reg & 3) + 8*(reg >> 2) + 4*lh;
                float x = a[reg] + Kcc[m] + bv;
                if (ok) oc[(size_t)m * NENT + n] = 1.f / (1.f + __expf(-x));
            }
        }
    }
}

extern "C" void kernel_launch(void* const* d_in, const int* in_sizes, int n_in,
                              void* d_out, int out_size, void* d_ws, size_t ws_size,
                              hipStream_t stream) {
    const float* E      = (const float*)d_in[0];
    const float* R      = (const float*)d_in[1];
    const float* psi    = (const float*)d_in[2];
    const float* gamma  = (const float*)d_in[3];
    const float* beta   = (const float*)d_in[4];
    const float* biases = (const float*)d_in[5];
    const int* h_idx    = (const int*)d_in[6];
    const int* r_idx    = (const int*)d_in[7];
    float* out = (float*)d_out;
    float* ws  = (float*)d_ws;

    _Float16* th = (_Float16*)(ws + WS_F16);
    _Float16* Eh = th + (size_t)4 * BATCH * DIM;

    hipMemsetAsync(ws + WS_ACC, 0, 4096 * sizeof(float), stream);

    convert_stats_kernel<<<512, 256, 0, stream>>>(E, Eh, ws + WS_ACC);
    stats_batch_kernel<<<16, 256, 0, stream>>>(E, h_idx, ws + WS_ACC + 2048);
    finalize_stats_kernel<<<4, 256, 0, stream>>>(ws + WS_ACC, ws + WS_STATS);
    build_t_kernel<<<BATCH, 256, 0, stream>>>(E, R, psi, gamma, beta, h_idx, r_idx,
                                              ws + WS_STATS, th, ws + WS_KC);
    dim3 grid((NENT + 127) / 128, BATCH / 128, 4);
    score_gemm_kernel<<<grid, 256, 0, stream>>>(th, Eh, ws + WS_KC, biases, out);
}

// Round 4
// 769.509 us; speedup vs baseline: 1.0242x; 1.0242x over previous
//
#include <hip/hip_runtime.h>
#include <math.h>

#define NENT 50000
#define NREL 500
#define DIM 256
#define BATCH 512
#define EPSV 1e-5f

// ws layout: floats [0,10240) = acc(4096) spare(4096) Kc(2048); then f16 tables
#define WS_ACC    0
#define WS_KC     8192
#define WS_F16    10240   // th: 4*512*256 halves, then Eh: 4*50000*256 halves

typedef _Float16 f16x8 __attribute__((ext_vector_type(8)));
typedef _Float16 f16x4 __attribute__((ext_vector_type(4)));
typedef float f32x4 __attribute__((ext_vector_type(4)));
typedef float f32x16 __attribute__((ext_vector_type(16)));

__device__ inline f32x16 zero16() {
    f32x16 v;
#pragma unroll
    for (int i = 0; i < 16; ++i) v[i] = 0.f;
    return v;
}

// ---------------- Phase 1 (fused): qnorm + f16 convert + BN stats (all-entity AND batch) ----
// Blocks 0..511: vectorized convert+stats over all entities.
// Blocks 512..527: batch-gather stats for h (writes acc[2048..4095]).
__global__ void convert_stats_kernel(const float* __restrict__ E, _Float16* __restrict__ Eh,
                                     float* __restrict__ acc, const int* __restrict__ h_idx) {
    if (blockIdx.x >= 512) {
        // ---- batch stats part ----
        int d = threadIdx.x;
        int b0 = (blockIdx.x - 512) * 32;
        float sm0=0,sm1=0,sm2=0,sm3=0, sq0=0,sq1=0,sq2=0,sq3=0;
        for (int j = 0; j < 32; ++j) {
            int n = h_idx[b0 + j];
            int ga = n*DIM + d;
            float e0 = E[ga];
            float e1 = E[1*NENT*DIM + ga];
            float e2 = E[2*NENT*DIM + ga];
            float e3 = E[3*NENT*DIM + ga];
            float inv = rsqrtf(e0*e0+e1*e1+e2*e2+e3*e3);
            e0*=inv; e1*=inv; e2*=inv; e3*=inv;
            sm0+=e0; sq0+=e0*e0;
            sm1+=e1; sq1+=e1*e1;
            sm2+=e2; sq2+=e2*e2;
            sm3+=e3; sq3+=e3*e3;
        }
        atomicAdd(&acc[2048 + 0*DIM+d], sm0); atomicAdd(&acc[3072 + 0*DIM+d], sq0);
        atomicAdd(&acc[2048 + 1*DIM+d], sm1); atomicAdd(&acc[3072 + 1*DIM+d], sq1);
        atomicAdd(&acc[2048 + 2*DIM+d], sm2); atomicAdd(&acc[3072 + 2*DIM+d], sq2);
        atomicAdd(&acc[2048 + 3*DIM+d], sm3); atomicAdd(&acc[3072 + 3*DIM+d], sq3);
        return;
    }

    __shared__ float red[3][64][33];   // j=1..3 partials (pad 33: avoid bank conflict)
    int tid = threadIdx.x;
    int dq = tid & 63, j = tid >> 6;
    int d0 = dq * 4;
    int per = (NENT + 511) / 512;
    int n0 = blockIdx.x * per;
    int n1 = n0 + per; if (n1 > NENT) n1 = NENT;

    float sm[4][4]; float sq[4][4];
#pragma unroll
    for (int c = 0; c < 4; ++c)
#pragma unroll
        for (int dd = 0; dd < 4; ++dd) { sm[c][dd] = 0.f; sq[c][dd] = 0.f; }

    for (int n = n0 + j; n < n1; n += 4) {
        size_t ga = (size_t)n * DIM + d0;
        f32x4 e[4];
        e[0] = *(const f32x4*)(E + ga);
        e[1] = *(const f32x4*)(E + (size_t)NENT * DIM + ga);
        e[2] = *(const f32x4*)(E + (size_t)2 * NENT * DIM + ga);
        e[3] = *(const f32x4*)(E + (size_t)3 * NENT * DIM + ga);
        float inv[4];
#pragma unroll
        for (int dd = 0; dd < 4; ++dd)
            inv[dd] = rsqrtf(e[0][dd]*e[0][dd] + e[1][dd]*e[1][dd] +
                             e[2][dd]*e[2][dd] + e[3][dd]*e[3][dd]);
#pragma unroll
        for (int c = 0; c < 4; ++c) {
            f16x4 hv;
#pragma unroll
            for (int dd = 0; dd < 4; ++dd) {
                float v = e[c][dd] * inv[dd];
                hv[dd] = (_Float16)v;
                sm[c][dd] += v; sq[c][dd] += v * v;
            }
            __builtin_nontemporal_store(hv, (f16x4*)(Eh + (size_t)c * NENT * DIM + ga));
        }
    }

    if (j > 0) {
        float* p = &red[j-1][dq][0];
#pragma unroll
        for (int c = 0; c < 4; ++c)
#pragma unroll
            for (int dd = 0; dd < 4; ++dd) {
                p[c*4 + dd]      = sm[c][dd];
                p[16 + c*4 + dd] = sq[c][dd];
            }
    }
    __syncthreads();
    if (j == 0) {
#pragma unroll
        for (int c = 0; c < 4; ++c)
#pragma unroll
            for (int dd = 0; dd < 4; ++dd) {
                float s = sm[c][dd] + red[0][dq][c*4+dd] + red[1][dq][c*4+dd] + red[2][dq][c*4+dd];
                float q = sq[c][dd] + red[0][dq][16+c*4+dd] + red[1][dq][16+c*4+dd] + red[2][dq][16+c*4+dd];
                atomicAdd(&acc[c*DIM + d0 + dd], s);
                atomicAdd(&acc[1024 + c*DIM + d0 + dd], q);
            }
    }
}

// ---------------- Phase 2: build t' (stats finalized inline, BN-folded, f16) and K[c][b] ----
__global__ void build_t_kernel(const float* __restrict__ E, const float* __restrict__ R,
                               const float* __restrict__ psi_emb,
                               const float* __restrict__ gamma, const float* __restrict__ beta,
                               const int* __restrict__ h_idx, const int* __restrict__ r_idx,
                               const float* __restrict__ acc,
                               _Float16* __restrict__ th, float* __restrict__ Kc) {
    __shared__ float red[4];
    int b = blockIdx.x, d = threadIdx.x;
    int wave = d >> 6, lane = d & 63;
    int hn = h_idx[b], rn = r_idx[b];

    // finalize BN stats from acc (4 KB, L2-hot, shared by all 512 blocks)
    float mE[4], isE[4], mH[4], isH[4];
#pragma unroll
    for (int c = 0; c < 4; ++c) {
        float a0 = acc[c*DIM + d];
        float a1 = acc[1024 + c*DIM + d];
        float a2 = acc[2048 + c*DIM + d];
        float a3 = acc[3072 + c*DIM + d];
        mE[c] = a0 * (1.0f / NENT);
        float vE = a1 * (1.0f / NENT) - mE[c] * mE[c];
        isE[c] = rsqrtf(vE + EPSV);
        mH[c] = a2 * (1.0f / BATCH);
        float vH = a3 * (1.0f / BATCH) - mH[c] * mH[c];
        isH[c] = rsqrtf(vH + EPSV);
    }

    float hv[4];
    hv[0] = E[hn*DIM + d];
    hv[1] = E[1*NENT*DIM + hn*DIM + d];
    hv[2] = E[2*NENT*DIM + hn*DIM + d];
    hv[3] = E[3*NENT*DIM + hn*DIM + d];
    float invh = rsqrtf(hv[0]*hv[0]+hv[1]*hv[1]+hv[2]*hv[2]+hv[3]*hv[3]);
    float hq[4];
#pragma unroll
    for (int c = 0; c < 4; ++c) {
        float v = hv[c] * invh;
        hq[c] = (v - mH[c]) * isH[c] * gamma[c*DIM + d] + beta[c*DIM + d];
    }

    float r0 = R[rn*DIM + d];
    float r1 = R[1*NREL*DIM + rn*DIM + d];
    float r2 = R[2*NREL*DIM + rn*DIM + d];
    float r3 = R[3*NREL*DIM + rn*DIM + d];
    float invr = rsqrtf(r0*r0+r1*r1+r2*r2+r3*r3);
    r0*=invr; r1*=invr; r2*=invr; r3*=invr;

    float p = psi_emb[rn*DIM + d];
    float cz = cosf(p), sz = sinf(p);

    float m1r = hq[0]*r0 - hq[1]*r1;
    float m1i = hq[0]*r1 + hq[1]*r0;
    float X   = hq[2]*r2 + hq[3]*r3;
    float Y   = hq[3]*r2 - hq[2]*r3;
    float m2r = cz*X - sz*Y;
    float m2i = cz*Y + sz*X;
    float m3r = hq[0]*r2 - hq[1]*r3;
    float m3i = hq[0]*r3 + hq[1]*r2;
    float U   = hq[2]*r0 + hq[3]*r1;
    float V   = hq[3]*r0 - hq[2]*r1;
    float m4r = cz*U - sz*V;
    float m4i = cz*V + sz*U;

    float t[4] = { m1r - m2r, m1i - m2i, m3r + m4r, m3i + m4i };

#pragma unroll
    for (int c = 0; c < 4; ++c) {
        float g   = gamma[c*DIM + d];
        th[((size_t)c*BATCH + b)*DIM + d] = (_Float16)(t[c] * g * isE[c]);
        float kp = t[c] * (beta[c*DIM + d] - g * mE[c] * isE[c]);
#pragma unroll
        for (int off = 32; off > 0; off >>= 1) kp += __shfl_down(kp, off, 64);
        if (lane == 0) red[wave] = kp;
        __syncthreads();
        if (d == 0) Kc[c*BATCH + b] = red[0] + red[1] + red[2] + red[3];
        __syncthreads();
    }
}

// ---------------- Phase 3: f16 MFMA GEMM + bias + sigmoid ----------------
// Block 128b x 128n, 4 waves (wave tile 64x64), K-chunk 32 (2 MFMA K-steps).
// Double-buffered with counted vmcnt(4) + raw s_barrier. Kc staged to LDS and
// biases preloaded to registers BEFORE the K-loop (epilogue never waits on HBM).
// Output + nothing-reused stores are nontemporal (no L2 allocation -> Eh panels survive).
__launch_bounds__(256)
__global__ void score_gemm_kernel(const _Float16* __restrict__ th,  // [4][512][256]
                                  const _Float16* __restrict__ Eh,  // [4][50000][256]
                                  const float* __restrict__ Kc,     // [4][512]
                                  const float* __restrict__ biases, // [4][50000]
                                  float* __restrict__ out) {        // [4][512][50000]
    __shared__ __align__(1024) char smem[32768 + 512];   // 2 buf x 16 frags x 1024B, then Kc[128]
    int tid = threadIdx.x;
    int w = tid >> 6, l = tid & 63;
    int lr = l & 31, lh = l >> 5;
    int wm = w & 1, wn = w >> 1;            // wave m-half / n-half

    // bijective chunked XCD swizzle: nwg = 391*4*4 = 6256 = 8 * 782
    int lin = blockIdx.x + (int)gridDim.x * (blockIdx.y + (int)gridDim.y * blockIdx.z);
    int wg  = (lin & 7) * 782 + (lin >> 3);
    int bt  = wg & 3;                       // b-tile fastest within a chunk
    int nt  = (wg >> 2) % 391;
    int c   = wg / 1564;                    // 391*4
    int b0  = bt * 128;
    int n0  = nt * 128;

    const _Float16* Ah = th + (size_t)c * BATCH * DIM;
    const _Float16* Bh = Eh + (size_t)c * NENT * DIM;
    const float* Kcc = Kc + c * BATCH;
    const float* bc  = biases + (size_t)c * NENT;

    // ---- pre-loop epilogue prefetch: biases -> regs, Kc row -> LDS ----
    int ng0 = n0 + wn*64 + lr;        // ni=0 column
    int ng1 = ng0 + 32;               // ni=1 column
    int ng0c = ng0 > NENT-1 ? NENT-1 : ng0;
    int ng1c = ng1 > NENT-1 ? NENT-1 : ng1;
    float bv0 = bc[ng0c];
    float bv1 = bc[ng1c];
    if (w < 2) {
        __builtin_amdgcn_global_load_lds(
            (const __attribute__((address_space(1))) void*)(Kcc + b0 + w*64 + l),
            (__attribute__((address_space(3))) void*)(smem + 32768 + w*256),
            4, 0, 0);
    }
    float* kcs = (float*)(smem + 32768);

    f32x16 acc00 = zero16(), acc01 = zero16(), acc10 = zero16(), acc11 = zero16();

    // stage one 32-wide K-chunk (16 frags of 1024B) into buffer slot
    auto stage = [&](int kc, int slot) {
        int kbase = kc * 32;
#pragma unroll
        for (int i = 0; i < 4; ++i) {
            int f = w * 4 + i;
            const _Float16* gp;
            if (f < 8) {                          // A frag: mf=f>>1, ks=f&1
                int mf = f >> 1, ks = f & 1;
                gp = Ah + (size_t)(b0 + mf*32 + lr) * DIM + kbase + ks*16 + lh*8;
            } else {                              // B frag
                int g = f - 8, nf = g >> 1, ks = g & 1;
                int n = n0 + nf*32 + lr; if (n > NENT-1) n = NENT-1;
                gp = Bh + (size_t)n * DIM + kbase + ks*16 + lh*8;
            }
            __builtin_amdgcn_global_load_lds(
                (const __attribute__((address_space(1))) void*)gp,
                (__attribute__((address_space(3))) void*)(smem + slot * 16384 + f * 1024),
                16, 0, 0);
        }
    };

    auto compute = [&](int slot) {
        const char* s = smem + slot * 16384;
#pragma unroll
        for (int ks = 0; ks < 2; ++ks) {
            f16x8 a0  = *(const f16x8*)(s + ((wm*2+0)*2 + ks)*1024 + l*16);
            f16x8 a1  = *(const f16x8*)(s + ((wm*2+1)*2 + ks)*1024 + l*16);
            f16x8 bb0 = *(const f16x8*)(s + 8192 + ((wn*2+0)*2 + ks)*1024 + l*16);
            f16x8 bb1 = *(const f16x8*)(s + 8192 + ((wn*2+1)*2 + ks)*1024 + l*16);
            acc00 = __builtin_amdgcn_mfma_f32_32x32x16_f16(a0, bb0, acc00, 0, 0, 0);
            acc01 = __builtin_amdgcn_mfma_f32_32x32x16_f16(a0, bb1, acc01, 0, 0, 0);
            acc10 = __builtin_amdgcn_mfma_f32_32x32x16_f16(a1, bb0, acc10, 0, 0, 0);
            acc11 = __builtin_amdgcn_mfma_f32_32x32x16_f16(a1, bb1, acc11, 0, 0, 0);
        }
    };

    stage(0, 0);                                  // prologue: chunk 0 -> buf 0
    for (int t = 0; t < 7; ++t) {
        stage(t + 1, (t + 1) & 1);                // prefetch next chunk (4 loads/wave)
        asm volatile("s_waitcnt vmcnt(4)" ::: "memory");   // chunk t (and pre-loop loads) done
        __builtin_amdgcn_s_barrier();
        compute(t & 1);
        __builtin_amdgcn_s_barrier();             // reads done before buf gets overwritten
    }
    asm volatile("s_waitcnt vmcnt(0)" ::: "memory");       // drain chunk 7
    __builtin_amdgcn_s_barrier();
    compute(1);                                   // chunk 7 -> buf 1

    // epilogue: D[m][n]: n = lane&31, m = (reg&3)+8*(reg>>2)+4*(lane>>5)
    float* oc = out + (size_t)c * BATCH * NENT;
#pragma unroll
    for (int mi = 0; mi < 2; ++mi) {
#pragma unroll
        for (int ni = 0; ni < 2; ++ni) {
            const f32x16& a = (mi==0) ? (ni==0 ? acc00 : acc01) : (ni==0 ? acc10 : acc11);
            int n = ni == 0 ? ng0 : ng1;
            bool ok = (n < NENT);
            float bv = ni == 0 ? bv0 : bv1;
#pragma unroll
            for (int reg = 0; reg < 16; ++reg) {
                int mloc = wm*64 + mi*32 + (reg & 3) + 8*(reg >> 2) + 4*lh;
                float x = a[reg] + kcs[mloc] + bv;
                float y = 1.f / (1.f + __expf(-x));
                if (ok) __builtin_nontemporal_store(y, &oc[(size_t)(b0 + mloc) * NENT + n]);
            }
        }
    }
}

extern "C" void kernel_launch(void* const* d_in, const int* in_sizes, int n_in,
                              void* d_out, int out_size, void* d_ws, size_t ws_size,
                              hipStream_t stream) {
    const float* E      = (const float*)d_in[0];
    const float* R      = (const float*)d_in[1];
    const float* psi    = (const float*)d_in[2];
    const float* gamma  = (const float*)d_in[3];
    const float* beta   = (const float*)d_in[4];
    const float* biases = (const float*)d_in[5];
    const int* h_idx    = (const int*)d_in[6];
    const int* r_idx    = (const int*)d_in[7];
    float* out = (float*)d_out;
    float* ws  = (float*)d_ws;

    _Float16* th = (_Float16*)(ws + WS_F16);
    _Float16* Eh = th + (size_t)4 * BATCH * DIM;

    hipMemsetAsync(ws + WS_ACC, 0, 4096 * sizeof(float), stream);

    convert_stats_kernel<<<528, 256, 0, stream>>>(E, Eh, ws + WS_ACC, h_idx);
    build_t_kernel<<<BATCH, 256, 0, stream>>>(E, R, psi, gamma, beta, h_idx, r_idx,
                                              ws + WS_ACC, th, ws + WS_KC);
    dim3 grid((NENT + 127) / 128, BATCH / 128, 4);
    score_gemm_kernel<<<grid, 256, 0, stream>>>(th, Eh, ws + WS_KC, biases, out);
}

// Round 5
// 765.417 us; speedup vs baseline: 1.0297x; 1.0053x over previous
//
#include <hip/hip_runtime.h>
#include <math.h>

#define NENT 50000
#define NREL 500
#define DIM 256
#define BATCH 512
#define EPSV 1e-5f

// ws layout: floats [0,10240) = acc(4096) spare(4096) Kc(2048); then f16 tables
#define WS_ACC    0
#define WS_KC     8192
#define WS_F16    10240   // th: 4*512*256 halves, then Eh: 4*50000*256 halves

typedef _Float16 f16x8 __attribute__((ext_vector_type(8)));
typedef _Float16 f16x4 __attribute__((ext_vector_type(4)));
typedef float f32x4 __attribute__((ext_vector_type(4)));
typedef float f32x16 __attribute__((ext_vector_type(16)));

__device__ inline f32x16 zero16() {
    f32x16 v;
#pragma unroll
    for (int i = 0; i < 16; ++i) v[i] = 0.f;
    return v;
}

// ---------------- Phase 1 (fused): qnorm + f16 convert + BN stats (all-entity AND batch) ----
// Blocks 0..511: vectorized convert+stats over all entities.
// Blocks 512..527: batch-gather stats for h (writes acc[2048..4095]).
__global__ void convert_stats_kernel(const float* __restrict__ E, _Float16* __restrict__ Eh,
                                     float* __restrict__ acc, const int* __restrict__ h_idx) {
    if (blockIdx.x >= 512) {
        // ---- batch stats part ----
        int d = threadIdx.x;
        int b0 = (blockIdx.x - 512) * 32;
        float sm0=0,sm1=0,sm2=0,sm3=0, sq0=0,sq1=0,sq2=0,sq3=0;
        for (int j = 0; j < 32; ++j) {
            int n = h_idx[b0 + j];
            int ga = n*DIM + d;
            float e0 = E[ga];
            float e1 = E[1*NENT*DIM + ga];
            float e2 = E[2*NENT*DIM + ga];
            float e3 = E[3*NENT*DIM + ga];
            float inv = rsqrtf(e0*e0+e1*e1+e2*e2+e3*e3);
            e0*=inv; e1*=inv; e2*=inv; e3*=inv;
            sm0+=e0; sq0+=e0*e0;
            sm1+=e1; sq1+=e1*e1;
            sm2+=e2; sq2+=e2*e2;
            sm3+=e3; sq3+=e3*e3;
        }
        atomicAdd(&acc[2048 + 0*DIM+d], sm0); atomicAdd(&acc[3072 + 0*DIM+d], sq0);
        atomicAdd(&acc[2048 + 1*DIM+d], sm1); atomicAdd(&acc[3072 + 1*DIM+d], sq1);
        atomicAdd(&acc[2048 + 2*DIM+d], sm2); atomicAdd(&acc[3072 + 2*DIM+d], sq2);
        atomicAdd(&acc[2048 + 3*DIM+d], sm3); atomicAdd(&acc[3072 + 3*DIM+d], sq3);
        return;
    }

    __shared__ float red[3][64][33];   // j=1..3 partials (pad 33: avoid bank conflict)
    int tid = threadIdx.x;
    int dq = tid & 63, j = tid >> 6;
    int d0 = dq * 4;
    int per = (NENT + 511) / 512;
    int n0 = blockIdx.x * per;
    int n1 = n0 + per; if (n1 > NENT) n1 = NENT;

    float sm[4][4]; float sq[4][4];
#pragma unroll
    for (int c = 0; c < 4; ++c)
#pragma unroll
        for (int dd = 0; dd < 4; ++dd) { sm[c][dd] = 0.f; sq[c][dd] = 0.f; }

    for (int n = n0 + j; n < n1; n += 4) {
        size_t ga = (size_t)n * DIM + d0;
        f32x4 e[4];
        e[0] = *(const f32x4*)(E + ga);
        e[1] = *(const f32x4*)(E + (size_t)NENT * DIM + ga);
        e[2] = *(const f32x4*)(E + (size_t)2 * NENT * DIM + ga);
        e[3] = *(const f32x4*)(E + (size_t)3 * NENT * DIM + ga);
        float inv[4];
#pragma unroll
        for (int dd = 0; dd < 4; ++dd)
            inv[dd] = rsqrtf(e[0][dd]*e[0][dd] + e[1][dd]*e[1][dd] +
                             e[2][dd]*e[2][dd] + e[3][dd]*e[3][dd]);
#pragma unroll
        for (int c = 0; c < 4; ++c) {
            f16x4 hv;
#pragma unroll
            for (int dd = 0; dd < 4; ++dd) {
                float v = e[c][dd] * inv[dd];
                hv[dd] = (_Float16)v;
                sm[c][dd] += v; sq[c][dd] += v * v;
            }
            __builtin_nontemporal_store(hv, (f16x4*)(Eh + (size_t)c * NENT * DIM + ga));
        }
    }

    if (j > 0) {
        float* p = &red[j-1][dq][0];
#pragma unroll
        for (int c = 0; c < 4; ++c)
#pragma unroll
            for (int dd = 0; dd < 4; ++dd) {
                p[c*4 + dd]      = sm[c][dd];
                p[16 + c*4 + dd] = sq[c][dd];
            }
    }
    __syncthreads();
    if (j == 0) {
#pragma unroll
        for (int c = 0; c < 4; ++c)
#pragma unroll
            for (int dd = 0; dd < 4; ++dd) {
                float s = sm[c][dd] + red[0][dq][c*4+dd] + red[1][dq][c*4+dd] + red[2][dq][c*4+dd];
                float q = sq[c][dd] + red[0][dq][16+c*4+dd] + red[1][dq][16+c*4+dd] + red[2][dq][16+c*4+dd];
                atomicAdd(&acc[c*DIM + d0 + dd], s);
                atomicAdd(&acc[1024 + c*DIM + d0 + dd], q);
            }
    }
}

// ---------------- Phase 2: build t' (stats finalized inline, BN-folded, f16) and K[c][b] ----
// Single reduction phase: kp[4] reduced together -> 1 barrier instead of 8.
__global__ void build_t_kernel(const float* __restrict__ E, const float* __restrict__ R,
                               const float* __restrict__ psi_emb,
                               const float* __restrict__ gamma, const float* __restrict__ beta,
                               const int* __restrict__ h_idx, const int* __restrict__ r_idx,
                               const float* __restrict__ acc,
                               _Float16* __restrict__ th, float* __restrict__ Kc) {
    __shared__ float red[16];          // [wave][c]
    int b = blockIdx.x, d = threadIdx.x;
    int wave = d >> 6, lane = d & 63;
    int hn = h_idx[b], rn = r_idx[b];

    // finalize BN stats from acc (4 KB, L2-hot, shared by all 512 blocks)
    float mE[4], isE[4], mH[4], isH[4];
#pragma unroll
    for (int c = 0; c < 4; ++c) {
        float a0 = acc[c*DIM + d];
        float a1 = acc[1024 + c*DIM + d];
        float a2 = acc[2048 + c*DIM + d];
        float a3 = acc[3072 + c*DIM + d];
        mE[c] = a0 * (1.0f / NENT);
        float vE = a1 * (1.0f / NENT) - mE[c] * mE[c];
        isE[c] = rsqrtf(vE + EPSV);
        mH[c] = a2 * (1.0f / BATCH);
        float vH = a3 * (1.0f / BATCH) - mH[c] * mH[c];
        isH[c] = rsqrtf(vH + EPSV);
    }

    float hv[4];
    hv[0] = E[hn*DIM + d];
    hv[1] = E[1*NENT*DIM + hn*DIM + d];
    hv[2] = E[2*NENT*DIM + hn*DIM + d];
    hv[3] = E[3*NENT*DIM + hn*DIM + d];
    float invh = rsqrtf(hv[0]*hv[0]+hv[1]*hv[1]+hv[2]*hv[2]+hv[3]*hv[3]);
    float hq[4];
#pragma unroll
    for (int c = 0; c < 4; ++c) {
        float v = hv[c] * invh;
        hq[c] = (v - mH[c]) * isH[c] * gamma[c*DIM + d] + beta[c*DIM + d];
    }

    float r0 = R[rn*DIM + d];
    float r1 = R[1*NREL*DIM + rn*DIM + d];
    float r2 = R[2*NREL*DIM + rn*DIM + d];
    float r3 = R[3*NREL*DIM + rn*DIM + d];
    float invr = rsqrtf(r0*r0+r1*r1+r2*r2+r3*r3);
    r0*=invr; r1*=invr; r2*=invr; r3*=invr;

    float p = psi_emb[rn*DIM + d];
    float cz = cosf(p), sz = sinf(p);

    float m1r = hq[0]*r0 - hq[1]*r1;
    float m1i = hq[0]*r1 + hq[1]*r0;
    float X   = hq[2]*r2 + hq[3]*r3;
    float Y   = hq[3]*r2 - hq[2]*r3;
    float m2r = cz*X - sz*Y;
    float m2i = cz*Y + sz*X;
    float m3r = hq[0]*r2 - hq[1]*r3;
    float m3i = hq[0]*r3 + hq[1]*r2;
    float U   = hq[2]*r0 + hq[3]*r1;
    float V   = hq[3]*r0 - hq[2]*r1;
    float m4r = cz*U - sz*V;
    float m4i = cz*V + sz*U;

    float t[4] = { m1r - m2r, m1i - m2i, m3r + m4r, m3i + m4i };

    float kp[4];
#pragma unroll
    for (int c = 0; c < 4; ++c) {
        float g = gamma[c*DIM + d];
        th[((size_t)c*BATCH + b)*DIM + d] = (_Float16)(t[c] * g * isE[c]);
        kp[c] = t[c] * (beta[c*DIM + d] - g * mE[c] * isE[c]);
    }
#pragma unroll
    for (int off = 32; off > 0; off >>= 1) {
#pragma unroll
        for (int c = 0; c < 4; ++c) kp[c] += __shfl_down(kp[c], off, 64);
    }
    if (lane == 0) {
#pragma unroll
        for (int c = 0; c < 4; ++c) red[wave*4 + c] = kp[c];
    }
    __syncthreads();
    if (d < 4)   // thread d handles component c=d
        Kc[d*BATCH + b] = red[0*4+d] + red[1*4+d] + red[2*4+d] + red[3*4+d];
}

// ---------------- Phase 3: f16 MFMA GEMM + bias + sigmoid ----------------
// Block 128b x 128n, 4 waves (wave tile 64x64), K-chunk 32 (2 MFMA K-steps).
// TRIPLE-BUFFERED, 2-deep prefetch: counted vmcnt(8) keeps chunks t+1 AND t+2
// in flight across barriers (never vmcnt(0) in steady state). Kc staged to LDS
// and biases preloaded to regs BEFORE the K-loop. Output stores nontemporal.
__launch_bounds__(256)
__global__ void score_gemm_kernel(const _Float16* __restrict__ th,  // [4][512][256]
                                  const _Float16* __restrict__ Eh,  // [4][50000][256]
                                  const float* __restrict__ Kc,     // [4][512]
                                  const float* __restrict__ biases, // [4][50000]
                                  float* __restrict__ out) {        // [4][512][50000]
    __shared__ __align__(1024) char smem[49152 + 512];   // 3 buf x 16 frags x 1024B, then Kc[128]
    int tid = threadIdx.x;
    int w = tid >> 6, l = tid & 63;
    int lr = l & 31, lh = l >> 5;
    int wm = w & 1, wn = w >> 1;            // wave m-half / n-half

    // bijective chunked XCD swizzle: nwg = 391*4*4 = 6256 = 8 * 782
    int lin = blockIdx.x + (int)gridDim.x * (blockIdx.y + (int)gridDim.y * blockIdx.z);
    int wg  = (lin & 7) * 782 + (lin >> 3);
    int bt  = wg & 3;                       // b-tile fastest within a chunk
    int nt  = (wg >> 2) % 391;
    int c   = wg / 1564;                    // 391*4
    int b0  = bt * 128;
    int n0  = nt * 128;

    const _Float16* Ah = th + (size_t)c * BATCH * DIM;
    const _Float16* Bh = Eh + (size_t)c * NENT * DIM;
    const float* Kcc = Kc + c * BATCH;
    const float* bc  = biases + (size_t)c * NENT;

    // ---- pre-loop epilogue prefetch: biases -> regs, Kc row -> LDS ----
    int ng0 = n0 + wn*64 + lr;        // ni=0 column
    int ng1 = ng0 + 32;               // ni=1 column
    int ng0c = ng0 > NENT-1 ? NENT-1 : ng0;
    int ng1c = ng1 > NENT-1 ? NENT-1 : ng1;
    float bv0 = bc[ng0c];
    float bv1 = bc[ng1c];
    if (w < 2) {
        __builtin_amdgcn_global_load_lds(
            (const __attribute__((address_space(1))) void*)(Kcc + b0 + w*64 + l),
            (__attribute__((address_space(3))) void*)(smem + 49152 + w*256),
            4, 0, 0);
    }
    float* kcs = (float*)(smem + 49152);

    f32x16 acc00 = zero16(), acc01 = zero16(), acc10 = zero16(), acc11 = zero16();

    // stage one 32-wide K-chunk (16 frags of 1024B) into buffer slot
    auto stage = [&](int kc, int slot) {
        int kbase = kc * 32;
#pragma unroll
        for (int i = 0; i < 4; ++i) {
            int f = w * 4 + i;
            const _Float16* gp;
            if (f < 8) {                          // A frag: mf=f>>1, ks=f&1
                int mf = f >> 1, ks = f & 1;
                gp = Ah + (size_t)(b0 + mf*32 + lr) * DIM + kbase + ks*16 + lh*8;
            } else {                              // B frag
                int g = f - 8, nf = g >> 1, ks = g & 1;
                int n = n0 + nf*32 + lr; if (n > NENT-1) n = NENT-1;
                gp = Bh + (size_t)n * DIM + kbase + ks*16 + lh*8;
            }
            __builtin_amdgcn_global_load_lds(
                (const __attribute__((address_space(1))) void*)gp,
                (__attribute__((address_space(3))) void*)(smem + slot * 16384 + f * 1024),
                16, 0, 0);
        }
    };

    auto compute = [&](int slot) {
        const char* s = smem + slot * 16384;
#pragma unroll
        for (int ks = 0; ks < 2; ++ks) {
            f16x8 a0  = *(const f16x8*)(s + ((wm*2+0)*2 + ks)*1024 + l*16);
            f16x8 a1  = *(const f16x8*)(s + ((wm*2+1)*2 + ks)*1024 + l*16);
            f16x8 bb0 = *(const f16x8*)(s + 8192 + ((wn*2+0)*2 + ks)*1024 + l*16);
            f16x8 bb1 = *(const f16x8*)(s + 8192 + ((wn*2+1)*2 + ks)*1024 + l*16);
            acc00 = __builtin_amdgcn_mfma_f32_32x32x16_f16(a0, bb0, acc00, 0, 0, 0);
            acc01 = __builtin_amdgcn_mfma_f32_32x32x16_f16(a0, bb1, acc01, 0, 0, 0);
            acc10 = __builtin_amdgcn_mfma_f32_32x32x16_f16(a1, bb0, acc10, 0, 0, 0);
            acc11 = __builtin_amdgcn_mfma_f32_32x32x16_f16(a1, bb1, acc11, 0, 0, 0);
        }
    };

    // prologue: chunks 0,1 in flight
    stage(0, 0);
    stage(1, 1);
    // 8 chunks total; steady state keeps 2 chunks (8 loads) in flight.
    // buf(t+2) was read at compute(t-1), separated by t-1's post-compute barrier: safe.
#pragma unroll 1
    for (int t = 0; t < 8; ++t) {
        if (t < 6) {
            stage(t + 2, (t + 2) % 3);
            asm volatile("s_waitcnt vmcnt(8)" ::: "memory");   // chunk t done; t+1,t+2 in flight
        } else if (t == 6) {
            asm volatile("s_waitcnt vmcnt(4)" ::: "memory");   // chunk 6 done; 7 in flight
        } else {
            asm volatile("s_waitcnt vmcnt(0)" ::: "memory");   // drain chunk 7 (+Kc on w<2)
        }
        __builtin_amdgcn_s_barrier();
        compute(t % 3);
        __builtin_amdgcn_s_barrier();
    }

    // epilogue: D[m][n]: n = lane&31, m = (reg&3)+8*(reg>>2)+4*(lane>>5)
    float* oc = out + (size_t)c * BATCH * NENT;
#pragma unroll
    for (int mi = 0; mi < 2; ++mi) {
#pragma unroll
        for (int ni = 0; ni < 2; ++ni) {
            const f32x16& a = (mi==0) ? (ni==0 ? acc00 : acc01) : (ni==0 ? acc10 : acc11);
            int n = ni == 0 ? ng0 : ng1;
            bool ok = (n < NENT);
            float bv = ni == 0 ? bv0 : bv1;
#pragma unroll
            for (int reg = 0; reg < 16; ++reg) {
                int mloc = wm*64 + mi*32 + (reg & 3) + 8*(reg >> 2) + 4*lh;
                float x = a[reg] + kcs[mloc] + bv;
                float y = 1.f / (1.f + __expf(-x));
                if (ok) __builtin_nontemporal_store(y, &oc[(size_t)(b0 + mloc) * NENT + n]);
            }
        }
    }
}

extern "C" void kernel_launch(void* const* d_in, const int* in_sizes, int n_in,
                              void* d_out, int out_size, void* d_ws, size_t ws_size,
                              hipStream_t stream) {
    const float* E      = (const float*)d_in[0];
    const float* R      = (const float*)d_in[1];
    const float* psi    = (const float*)d_in[2];
    const float* gamma  = (const float*)d_in[3];
    const float* beta   = (const float*)d_in[4];
    const float* biases = (const float*)d_in[5];
    const int* h_idx    = (const int*)d_in[6];
    const int* r_idx    = (const int*)d_in[7];
    float* out = (float*)d_out;
    float* ws  = (float*)d_ws;

    _Float16* th = (_Float16*)(ws + WS_F16);
    _Float16* Eh = th + (size_t)4 * BATCH * DIM;

    hipMemsetAsync(ws + WS_ACC, 0, 4096 * sizeof(float), stream);

    convert_stats_kernel<<<528, 256, 0, stream>>>(E, Eh, ws + WS_ACC, h_idx);
    build_t_kernel<<<BATCH, 256, 0, stream>>>(E, R, psi, gamma, beta, h_idx, r_idx,
                                              ws + WS_ACC, th, ws + WS_KC);
    dim3 grid((NENT + 127) / 128, BATCH / 128, 4);
    score_gemm_kernel<<<grid, 256, 0, stream>>>(th, Eh, ws + WS_KC, biases, out);
}